// Round 1
// 182.167 us; speedup vs baseline: 1.0593x; 1.0593x over previous
//
#include <hip/hip_runtime.h>
#include <hip/hip_bf16.h>

#define EPSBN 1e-5f

typedef short short8 __attribute__((ext_vector_type(8)));
typedef float f32x16 __attribute__((ext_vector_type(16)));

static __device__ __forceinline__ unsigned short f2u(float f){
  __hip_bfloat16 h = __float2bfloat16(f);
  union { __hip_bfloat16 h; unsigned short u; } c; c.h = h; return c.u;
}

// ---- workspace layout (bytes) ----
#define WS_G     2048
#define WS_S     7168
#define WS_T     8192
#define WS_AGGB  16384      // 147456 bf16  [b][cc2][s9][o32][ci32]
#define WS_XUP   327680     // 33554432 bf16 [b][h16(4)][r256][c256][ci16]  (plane = 1<<20 halfwords)

#define XIN_S 820           // per-ci float stride (820%4==0 for float4; 2*820 % 32 = 8 -> 2-way banks)

// ------- K1: bilinear x2 upsample -> bf16 planes [b][h16][r][c][ci16], GAP fused -------
// grid: 1024 = b(8) x h16(4) x strip(32 of 8 rows)
__global__ __launch_bounds__(256) void k_up(const float* __restrict__ x,
                                            unsigned int* __restrict__ xup32,
                                            float* __restrict__ g)
{
  __shared__ float xin[16*XIN_S];   // [ci16][ir6][j136: 128 data + 8 zero pad]
  __shared__ float w[128];
  int tid = threadIdx.x;
  int bi  = blockIdx.x;
  int strip = bi & 31, h16 = (bi >> 5) & 3, b = bi >> 7;
  int r0 = strip * 8;
  int i0b = (int)((float)r0 * (127.0f/255.0f));

  if (tid < 128){
    int i = tid;
    float s = 0.f;
    int rstart = max(0, (int)floorf((float)(i-1)*(255.0f/127.0f)));
    #pragma unroll
    for (int k = 0; k < 8; ++k){
      int r = rstart + k;
      if (r <= 255){
        float pos = (float)r * (127.0f/255.0f);
        int i0 = (int)pos; float fr = pos - (float)i0; int i1 = min(i0+1,127);
        if (i0 == i) s += 1.0f - fr;
        if (i1 == i) s += fr;
      }
    }
    w[i] = s;
  }
  // main loads: float4 vectorized (3072 granules of 4 floats)
  for (int e4 = tid; e4 < 3072; e4 += 256){
    int j4 = e4 & 31, ci = (e4 >> 5) & 15, ir = e4 >> 9;
    int row = min(i0b + ir, 127);
    *(float4*)&xin[ci*XIN_S + ir*136 + j4*4] =
      *(const float4*)&x[(((size_t)(b*64 + h16*16 + ci)) << 14) + (row << 7) + j4*4];
  }
  // zero pad cols 128..135 so j0+1 reads never see garbage
  for (int e2 = tid; e2 < 768; e2 += 256){
    int k = e2 & 7, t8 = e2 >> 3;
    int ir = t8 % 6, ci = t8 / 6;
    xin[ci*XIN_S + ir*136 + 128 + k] = 0.f;
  }
  __syncthreads();

  // ---- GAP partial: rows 4*strip..4*strip+3 (disjoint across strips), from LDS ----
  {
    int ci_l = tid >> 4, kk = tid & 15;
    float s = 0.f;
    const float* base = &xin[ci_l*XIN_S];
    #pragma unroll
    for (int row = 0; row < 4; ++row){
      int grow = 4*strip + row;
      int ir = grow - i0b;          // in [0,5] by construction
      const float* rp = base + ir*136 + kk*8;
      float ss = 0.f;
      #pragma unroll
      for (int j = 0; j < 8; ++j) ss += rp[j]*w[kk*8+j];
      s += w[grow]*ss;
    }
    s += __shfl_down(s, 8, 16);
    s += __shfl_down(s, 4, 16);
    s += __shfl_down(s, 2, 16);
    s += __shfl_down(s, 1, 16);
    if (kk == 0) atomicAdd(&g[b*64 + h16*16 + ci_l], s*(1.0f/65536.0f));
  }

  // ---- interp phase: horizontal-first, rolling 2-row register cache ----
  int ci2 = tid & 7, cbase = tid >> 3;   // cbase 0..31; cols c = cbase + 32*jj (store-coalesced)
  const float* b0p = &xin[(ci2*2+0)*XIN_S];
  const float* b1p = &xin[(ci2*2+1)*XIN_S];
  size_t plane32 = ((size_t)(b*4 + h16)) << 19;   // plane base in dwords

  #pragma unroll
  for (int jj = 0; jj < 8; ++jj){
    int c = cbase + 32*jj;
    float pos = (float)c * (127.0f/255.0f);
    int j0 = (int)pos; float ww = pos - (float)j0;

    // rolling vertical state: A = h-lerp(row irA), B = h-lerp(row irA+1)
    int irA = 0;
    float A0, B0, A1, B1;
    {
      float x0 = b0p[j0],     x1 = b0p[j0+1];     A0 = x0 + (x1-x0)*ww;
      float y0 = b1p[j0],     y1 = b1p[j0+1];     A1 = y0 + (y1-y0)*ww;
      float x2 = b0p[136+j0], x3 = b0p[136+j0+1]; B0 = x2 + (x3-x2)*ww;
      float y2 = b1p[136+j0], y3 = b1p[136+j0+1]; B1 = y2 + (y3-y2)*ww;
    }
    #pragma unroll
    for (int rr = 0; rr < 8; ++rr){
      int r = r0 + rr;
      float posr = (float)r * (127.0f/255.0f);
      int i0 = (int)posr; float wh = posr - (float)i0;
      int ir0 = i0 - i0b;
      if (ir0 > irA){                 // wave-uniform branch (all threads share strip)
        A0 = B0; A1 = B1;
        int irB = ir0 + 1;            // <= 5 by construction
        float x0 = b0p[irB*136+j0], x1 = b0p[irB*136+j0+1]; B0 = x0 + (x1-x0)*ww;
        float y0 = b1p[irB*136+j0], y1 = b1p[irB*136+j0+1]; B1 = y0 + (y1-y0)*ww;
        irA = ir0;
      }
      float r0v = A0 + (B0-A0)*wh;
      float r1v = A1 + (B1-A1)*wh;
      unsigned pack = (unsigned)f2u(r0v) | (((unsigned)f2u(r1v)) << 16);
      xup32[plane32 + (size_t)(r*256 + c)*8 + ci2] = pack;
    }
  }
}

// ------- K2: attention MLP (redundant per block) + aggregated bf16 filters -------
// layout out: [b][cc2][s9][o32][ci32]
__global__ __launch_bounds__(256) void k_aggw(const float* __restrict__ g,
                      const float* __restrict__ fc_w,
                      const float* __restrict__ bga, const float* __restrict__ bba,
                      const float* __restrict__ bma, const float* __restrict__ bva,
                      const float* __restrict__ ch_w, const float* __restrict__ ch_b,
                      const float* __restrict__ fil_w, const float* __restrict__ fil_b,
                      const float* __restrict__ sp_w, const float* __restrict__ sp_b,
                      const float* __restrict__ k_w, const float* __restrict__ k_b,
                      const float* __restrict__ bn_g, const float* __restrict__ bn_b,
                      const float* __restrict__ bn_m, const float* __restrict__ bn_v,
                      const float* __restrict__ weight,
                      unsigned short* __restrict__ aggb,
                      float* __restrict__ sS, float* __restrict__ tT)
{
  __shared__ float h[8][16];
  int tid = threadIdx.x;
  if (tid < 128){
    int b = tid >> 4, a = tid & 15;
    float acc = 0.f;
    for (int c = 0; c < 64; ++c) acc += g[b*64+c] * fc_w[a*64+c];
    float v = (acc - bma[a]) * rsqrtf(bva[a] + EPSBN) * bga[a] + bba[a];
    h[b][a] = fmaxf(v, 0.f);
  }
  __syncthreads();

  int idx = blockIdx.x*256 + tid;      // < 147456
  int ci_l = idx & 31;
  int o    = (idx >> 5) & 31;
  int s    = (idx >> 10) % 9;
  int t2   = (idx >> 10) / 9;          // b*2+cc
  int cc   = t2 & 1, b = t2 >> 1;
  int ci   = cc*32 + ci_l;

  const float* hb = h[b];
  float zc = ch_b[ci], zs = sp_b[s];
  float z0 = k_b[0],  z1 = k_b[1];
  #pragma unroll
  for (int a = 0; a < 16; ++a){
    float hv = hb[a];
    zc += hv*ch_w[ci*16+a];
    zs += hv*sp_w[s*16+a];
    z0 += hv*k_w[a];
    z1 += hv*k_w[16+a];
  }
  float chv = 1.f/(1.f+expf(-zc));
  float spv = 1.f/(1.f+expf(-zs));
  float m = fmaxf(z0,z1);
  float e0 = expf(z0-m), e1 = expf(z1-m), inv = 1.f/(e0+e1);
  float ka0 = e0*inv, ka1 = e1*inv;
  float w0 = weight[(o*64+ci)*9+s];
  float w1 = weight[((32+o)*64+ci)*9+s];
  aggb[idx] = f2u(chv*spv*(ka0*w0 + ka1*w1));

  if (blockIdx.x == 0){
    int bb = tid >> 5, oo = tid & 31;
    float z = fil_b[oo];
    #pragma unroll
    for (int a = 0; a < 16; ++a) z += h[bb][a]*fil_w[oo*16+a];
    float f = 1.f/(1.f+expf(-z));
    float invs = rsqrtf(bn_v[oo] + EPSBN);
    sS[tid] = f * bn_g[oo] * invs;
    if (bb == 0) tT[oo] = bn_b[oo] - bn_m[oo]*bn_g[oo]*invs;
  }
}

// -------- K3: MFMA implicit-GEMM conv + BN + GELU --------
// block: 16x32 output px, all 32 Cout; 4 waves x 4 acc tiles; 2 cc chunks of 32 ci.
// cc=1 input tile prefetched into registers before cc=0 K-loop; A-frags s-pipelined.
// XCD-chunked swizzle: each XCD owns one b -> halo + plane reuse in its private L2.
#define XT_STRIDE 40   // 32 ci + 8 pad halfwords (80 B, 16B-aligned, bank-balanced)

__global__ __launch_bounds__(256) void k_conv(const unsigned short* __restrict__ xup,
                                              const unsigned short* __restrict__ aggb,
                                              const float* __restrict__ sS,
                                              const float* __restrict__ tT,
                                              float* __restrict__ out)
{
  __shared__ unsigned short xt[18*34*XT_STRIDE];   // 48960 B
  __shared__ float sSs[32], tTs[32];

  int tid = threadIdx.x;
  int bi  = blockIdx.x;
  int sw  = ((bi & 7) << 7) + (bi >> 3);     // nwg=1024 -> xcd*128 + idx (bijective)
  int b   = sw >> 7, t = sw & 127;
  int p0  = (t >> 3) * 16, q0 = (t & 7) * 32;
  int lane = tid & 63, wv = tid >> 6;
  if (tid < 32){ sSs[tid] = sS[b*32+tid]; tTs[tid] = tT[tid]; }

  f32x16 acc[4];
  #pragma unroll
  for (int i = 0; i < 16; ++i){ acc[0][i]=0.f; acc[1][i]=0.f; acc[2][i]=0.f; acc[3][i]=0.f; }

  int n     = lane & 31;        // Cout row for A, px col for B/C
  int kq    = lane >> 5;        // k-half
  int rhalf = n >> 4;
  int qb    = n & 15;
  int wrow  = wv * 4;           // wave owns px rows wrow..wrow+3

  const unsigned short* xb0 = xup + (((size_t)(b*4 + 0)) << 20);
  const unsigned short* xb1 = xup + (((size_t)(b*4 + 2)) << 20);
  const short8 zero8 = {0,0,0,0,0,0,0,0};

  // stage cc=0 tile + prefetch cc=1 into registers (all 20 loads in flight pre-barrier)
  short8 pre[10];
  #pragma unroll
  for (int k = 0; k < 10; ++k){
    int e = tid + (k << 8); if (e >= 2448) e -= 2448;   // wrap dupes benign
    int rr = e / 136, rem = e - rr*136;
    int qq = rem >> 2, k2 = (rem >> 1) & 1, kqe = rem & 1;
    int gr = p0 - 1 + rr, gq = q0 - 1 + qq;
    bool v = ((unsigned)gr < 256u) && ((unsigned)gq < 256u);
    int ldso = (rr*34 + qq)*XT_STRIDE + k2*16 + kqe*8;
    int pmo  = (k2 << 20) + (gr*256 + gq)*16 + kqe*8;
    short8 cur = zero8; pre[k] = zero8;
    if (v){ cur = *(const short8*)&xb0[pmo]; pre[k] = *(const short8*)&xb1[pmo]; }
    *(short8*)&xt[ldso] = cur;
  }
  __syncthreads();

  // K-loop over a cc chunk; A-fragments software-pipelined, shared by 4 acc tiles
  auto kloop = [&](const unsigned short* ab){
    short8 a0 = *(const short8*)&ab[0];
    short8 a1 = *(const short8*)&ab[16];
    #pragma unroll
    for (int s = 0; s < 9; ++s){
      int sn = (s < 8) ? s+1 : 8;
      short8 na0 = *(const short8*)&ab[sn*1024];
      short8 na1 = *(const short8*)&ab[sn*1024+16];
      const int ky = s/3, kx = s%3;
      #pragma unroll
      for (int tt = 0; tt < 4; ++tt){
        const int rp = tt >> 1, cb = tt & 1;
        const unsigned short* xrow =
          &xt[((wrow + 2*rp + rhalf + ky)*34 + cb*16 + qb + kx)*XT_STRIDE + kq*8];
        short8 bv0 = *(const short8*)&xrow[0];
        short8 bv1 = *(const short8*)&xrow[16];
        acc[tt] = __builtin_amdgcn_mfma_f32_32x32x16_bf16(a0, bv0, acc[tt], 0, 0, 0);
        acc[tt] = __builtin_amdgcn_mfma_f32_32x32x16_bf16(a1, bv1, acc[tt], 0, 0, 0);
      }
      a0 = na0; a1 = na1;
    }
  };

  kloop(aggb + (size_t)(b*2+0)*9216 + n*32 + kq*8);
  __syncthreads();
  // commit prefetched cc=1 tile
  #pragma unroll
  for (int k = 0; k < 10; ++k){
    int e = tid + (k << 8); if (e >= 2448) e -= 2448;
    int rr = e / 136, rem = e - rr*136;
    int qq = rem >> 2, k2 = (rem >> 1) & 1, kqe = rem & 1;
    int ldso = (rr*34 + qq)*XT_STRIDE + k2*16 + kqe*8;
    *(short8*)&xt[ldso] = pre[k];
  }
  __syncthreads();
  kloop(aggb + (size_t)(b*2+1)*9216 + n*32 + kq*8);

  // epilogue: scale/bias + GELU(exact erf), fp32 stores
  #pragma unroll
  for (int tt = 0; tt < 4; ++tt){
    int rp = tt >> 1, cb = tt & 1;
    int p = p0 + wrow + 2*rp + rhalf;
    int q = q0 + cb*16 + qb;
    #pragma unroll
    for (int r = 0; r < 16; ++r){
      int o = (r & 3) + 8*(r >> 2) + 4*kq;
      float valv = acc[tt][r]*sSs[o] + tTs[o];
      float gl  = 0.5f*valv*(1.f + erff(valv*0.70710678118f));
      out[(((size_t)(b*32+o)) << 16) + (p << 8) + q] = gl;
    }
  }
}

extern "C" void kernel_launch(void* const* d_in, const int* in_sizes, int n_in,
                              void* d_out, int out_size, void* d_ws, size_t ws_size,
                              hipStream_t stream)
{
  const float* x     = (const float*)d_in[0];
  const float* fc_w  = (const float*)d_in[1];
  const float* bga   = (const float*)d_in[2];
  const float* bba   = (const float*)d_in[3];
  const float* bma   = (const float*)d_in[4];
  const float* bva   = (const float*)d_in[5];
  const float* ch_w  = (const float*)d_in[6];
  const float* ch_b  = (const float*)d_in[7];
  const float* fil_w = (const float*)d_in[8];
  const float* fil_b = (const float*)d_in[9];
  const float* sp_w  = (const float*)d_in[10];
  const float* sp_b  = (const float*)d_in[11];
  const float* k_w   = (const float*)d_in[12];
  const float* k_b   = (const float*)d_in[13];
  const float* weight= (const float*)d_in[14];
  const float* bn_g  = (const float*)d_in[15];
  const float* bn_b  = (const float*)d_in[16];
  const float* bn_m  = (const float*)d_in[17];
  const float* bn_v  = (const float*)d_in[18];

  char* ws = (char*)d_ws;
  float* g   = (float*)(ws + WS_G);
  float* sS  = (float*)(ws + WS_S);
  float* tT  = (float*)(ws + WS_T);
  unsigned short* aggb = (unsigned short*)(ws + WS_AGGB);
  unsigned short* xup  = (unsigned short*)(ws + WS_XUP);
  float* out = (float*)d_out;

  hipMemsetAsync(g, 0, 512*sizeof(float), stream);
  hipLaunchKernelGGL(k_up,   dim3(1024), dim3(256), 0, stream, x, (unsigned int*)xup, g);
  hipLaunchKernelGGL(k_aggw, dim3(576),  dim3(256), 0, stream, g, fc_w, bga, bba, bma, bva,
                     ch_w, ch_b, fil_w, fil_b, sp_w, sp_b, k_w, k_b,
                     bn_g, bn_b, bn_m, bn_v, weight, aggb, sS, tT);
  hipLaunchKernelGGL(k_conv, dim3(1024), dim3(256), 0, stream, xup, aggb, sS, tT, out);
}